// Round 11
// baseline (813.206 us; speedup 1.0000x reference)
//
#include <hip/hip_runtime.h>

#define BB     128
#define MM     4096
#define NN     8192
#define DEG    12
#define RDEG   11          // edges 0..10 real; edge 11 is ALWAYS the dummy (col==NN)
#define MAXIT  8
#define BLOCK  1024
#define HALF_M 2048        // check rows per block (2 blocks per batch)
#define NW     4096        // full l_v: 2 vars per word, u16 halves biased +32768
#define BIAS   32768
#define BIG    (1 << 20)
#define ACCB   0x80008000u // per-iteration accumulator bias (both halves +0x8000)
#define NFLAGS (BB * 9 * 2)

__device__ __forceinline__ int quantI(float x) {   // fp2fxp -> integer units of 1/16
    float r = rintf(x * 16.0f);                    // RNE, matches jnp.round
    r = fminf(r, 127.0f);
    r = fmaxf(r, -128.0f);
    return (int)r;
}
__device__ __forceinline__ int clamp8(int t) { return max(-128, min(127, t)); }
__device__ __forceinline__ int rne4(int t) {       // RNE of t/16, t >= 0
    const int r = t >> 4, rem = t & 15;
    return r + (((rem > 8) || (rem == 8 && (r & 1))) ? 1 : 0);
}

// Columns in LDS (u16); one row = 12 u16 = 24 B -> three ds_read_b64.
struct Cols { ushort4 a, b, c; };
__device__ __forceinline__ Cols loadCols(const unsigned short* colT, int row) {
    const ushort4* p = (const ushort4*)(colT + row * DEG);
    Cols C; C.a = p[0]; C.b = p[1]; C.c = p[2]; return C;
}
__device__ __forceinline__ int colOf(const Cols& C, int d) {
    switch (d) {
        case 0: return C.a.x; case 1: return C.a.y; case 2: return C.a.z; case 3: return C.a.w;
        case 4: return C.b.x; case 5: return C.b.y; case 6: return C.b.z; case 7: return C.b.w;
        case 8: return C.c.x; case 9: return C.c.y; default: return C.c.z;
    }
}

// Merge one packed word: biased_half = u0_half + accA_half + accB_half - 2*0x8000.
// Halves unpacked so the 3-way sum's carry cannot cross bit 16.
#define MRG(DST, U, A, Pp) {                                                   \
    const int lo_ = ((U) & 0xffff) + ((A) & 0xffff) + ((Pp) & 0xffff) - 0x10000; \
    const int hi_ = (int)(((unsigned)(U)) >> 16) + (int)(((unsigned)(A)) >> 16)  \
                  + (int)(((unsigned)(Pp)) >> 16) - 0x10000;                   \
    DST = (hi_ << 16) | (lo_ & 0xffff); }

// One check-row (proven-exact math from R10). Scatter target is always acc.
#define ROW(KK, FIRSTF, LU, CC_, FBI, FB1, NEXTCODE) do {                      \
    int sbits = 0, par = 0, min0 = BIG, min1 = BIG;                            \
    int aa[RDEG];                                                              \
    _Pragma("unroll") for (int d = 0; d < RDEG; ++d) {                         \
        const int m = FIRSTF ? 0 :                                             \
            (int)(signed char)((msgp[KK][d >> 2] >> ((d & 3) * 8)) & 0xffu);   \
        const int l = LU[d] - BIAS;                                            \
        par ^= (l <= 0);                                                       \
        const int av = clamp8(l - m);                                          \
        const int t = abs(av);                                                 \
        sbits |= (av <= 0) << d;                                               \
        min1 = min(min1, max(min0, t)); min0 = min(min0, t);                   \
        aa[d] = t; }                                                           \
    if (!FIRSTF) {                                                             \
        /* dummy edge a = fxp(inf-0) = 7.9375 -> 127: joins mins, clamps both */\
        min1 = min(min1, max(min0, 127)); min0 = min(min0, 127);               \
        mism |= par ^ ((synbits >> KK) & 1); }                                 \
    int eqb = 0;                                                               \
    _Pragma("unroll") for (int d = 0; d < RDEG; ++d)                           \
        eqb |= (aa[d] == min0) << d;                                           \
    NEXTCODE;                                                                  \
    const int qsb = ((synbits >> KK) & 1) ^ (__popc(sbits) & 1);               \
    const int m0C = FIRSTF ? min(min0, 127) : min0;                            \
    const int m1C = FIRSTF ? min(min1, 127) : min1;                            \
    const int q0 = FB1 ? m0C : rne4(m0C * FBI);                                \
    const int q1 = FB1 ? m1C : rne4(m1C * FBI);                                \
    unsigned nm0 = 0u, nm1 = 0u, nm2 = 0u;                                     \
    _Pragma("unroll") for (int d = 0; d < RDEG; ++d) {                         \
        const int q = ((eqb >> d) & 1) ? q1 : q0;                              \
        const int s = ((sbits >> d) & 1) ^ qsb;                                \
        const int bv = s ? -q : q;                                             \
        if (d < 4)      nm0 |= ((unsigned)bv & 0xffu) << (d * 8);              \
        else if (d < 8) nm1 |= ((unsigned)bv & 0xffu) << ((d - 4) * 8);        \
        else            nm2 |= ((unsigned)bv & 0xffu) << ((d - 8) * 8);        \
        if (bv != 0) {                                                         \
            const int col = colOf(CC_, d);                                     \
            atomicAdd(&acc[col >> 1], (int)((unsigned)bv << ((col & 1) << 4))); } } \
    msgp[KK][0] = nm0; msgp[KK][1] = nm1; msgp[KK][2] = nm2;                   \
} while (0)

#define PIDX(IT, HH) ((b * 9 + (IT) - 1) * 2 + (HH))

// Fence + signal + spin + lastbad pickup. Flags are zeroed by hipMemsetAsync
// every call, so the rendezvous is stale-state-proof under graph replay.
#define SYNCPAIR(IT)                                                           \
    __threadfence();                                                           \
    __syncthreads();                                                           \
    if (tid == 0) {                                                            \
        __hip_atomic_store(&prod[PIDX(IT, h)], 1, __ATOMIC_RELEASE,            \
                           __HIP_MEMORY_SCOPE_AGENT);                          \
        while (__hip_atomic_load(&prod[PIDX(IT, 1 - h)], __ATOMIC_ACQUIRE,     \
                                 __HIP_MEMORY_SCOPE_AGENT) == 0)               \
            __builtin_amdgcn_s_sleep(1);                                       \
        lb_sh = __hip_atomic_load(&lastbad_g[b], __ATOMIC_RELAXED,             \
                                  __HIP_MEMORY_SCOPE_AGENT);                   \
    }                                                                          \
    __syncthreads();

// One iteration. P (0/1) selects the mailbox slot pair (reuse distance 2 is
// safe: partner's read of slot[it-2] happens-before its prod[it-1] signal,
// which we awaited before writing slot[it]).
#define ITER(IT, FIRSTF, P, CUR, NXT, FBI, FB1) {                              \
    const unsigned short* curS = (const unsigned short*)(CUR);                 \
    int mism = 0; (void)mism;                                                  \
    int luA[RDEG], luB[RDEG];                                                  \
    _Pragma("unroll") for (int d = 0; d < RDEG; ++d)                           \
        luA[d] = (int)curS[colOf(c0, d)];                                      \
    ROW(0, FIRSTF, luA, c0, FBI, FB1, {                                        \
        _Pragma("unroll") for (int d = 0; d < RDEG; ++d)                       \
            luB[d] = (int)curS[colOf(c1, d)]; });                              \
    ROW(1, FIRSTF, luB, c1, FBI, FB1, {                                        \
        c0 = loadCols(colT, tid); c1 = loadCols(colT, tid + BLOCK); });        \
    if (!FIRSTF) { if (__any(mism) && (tid & 63) == 0)                         \
        atomicMax(&lastbad_g[b], IT); }                                        \
    __syncthreads();                               /* acc atomics complete */  \
    const int4 av = ((int4*)acc)[tid];                                         \
    ((int4*)acc)[tid] = make_int4((int)ACCB, (int)ACCB, (int)ACCB, (int)ACCB); \
    { int* mb = ((P) ? mbL : mbE) + (size_t)h * NW;                            \
      ((int4*)mb)[tid] = av; }                                                 \
    SYNCPAIR(IT);                                                              \
    if (!FIRSTF && lb_sh < (IT)) { conv_it = (IT) - 1; outP = (CUR); goto done_label; } \
    { const int* pmb = ((P) ? mbL : mbE) + (size_t)(1 - h) * NW;               \
      const int pa0 = __hip_atomic_load((int*)&pmb[4 * tid + 0], __ATOMIC_RELAXED, __HIP_MEMORY_SCOPE_AGENT); \
      const int pa1 = __hip_atomic_load((int*)&pmb[4 * tid + 1], __ATOMIC_RELAXED, __HIP_MEMORY_SCOPE_AGENT); \
      const int pa2 = __hip_atomic_load((int*)&pmb[4 * tid + 2], __ATOMIC_RELAXED, __HIP_MEMORY_SCOPE_AGENT); \
      const int pa3 = __hip_atomic_load((int*)&pmb[4 * tid + 3], __ATOMIC_RELAXED, __HIP_MEMORY_SCOPE_AGENT); \
      int mg0, mg1, mg2, mg3;                                                  \
      MRG(mg0, u0a, av.x, pa0); MRG(mg1, u0b, av.y, pa1);                      \
      MRG(mg2, u0c, av.z, pa2); MRG(mg3, u0d, av.w, pa3);                      \
      ((int4*)(NXT))[tid] = make_int4(mg0, mg1, mg2, mg3); }                   \
    __syncthreads();                               /* NXT ready for gathers */ \
}

__global__ __launch_bounds__(BLOCK, 4)
__attribute__((amdgpu_waves_per_eu(4, 4)))
void ldpc_kernel(const float* __restrict__ synd,
                 const float* __restrict__ llr0,
                 const int*  __restrict__ Vcol,
                 float* __restrict__ out,
                 int*  __restrict__ flags)
{
    __shared__ __align__(16) int lvX[NW];                    // 16 KB
    __shared__ __align__(16) int lvY[NW];                    // 16 KB
    __shared__ __align__(16) int acc[NW];                    // 16 KB
    __shared__ __align__(16) unsigned short colT[HALF_M * DEG]; // 48 KB
    __shared__ int lb_sh;                                    // ~96 KB -> 1 block/CU

    const int bid = blockIdx.x;
    const int b   = bid & (BB - 1);     // batch
    const int h   = bid >> 7;           // half: pair (b, b+128) -> same XCD heuristic
    const int tid = threadIdx.x;

    const float* llr_b  = llr0 + (size_t)b * NN;
    const float* synd_b = synd + (size_t)b * MM;
    int* const prod      = flags;
    int* const lastbad_g = flags + NFLAGS;
    // Mailboxes live inside batch b's OWN output region (e_out for parity 0,
    // l_out for parity 1): 2 slots x 2 halves x 16 KB = exactly this batch's
    // 64 KB of e/l output -> no cross-pair aliasing; epilogue overwrites only
    // after all mailbox use is done.
    int* const mbE = (int*)out + (size_t)b * (2 * NW);
    int* const mbL = (int*)out + (size_t)(BB * NN + BB) + (size_t)b * (2 * NW);

    // ---- colT: this block's 2048 rows (coalesced int4 reads) ----
    {
        const int4* vg = (const int4*)(Vcol + (size_t)h * HALF_M * DEG); // 6144 int4
        ushort4*    ct = (ushort4*)colT;
        #pragma unroll
        for (int j = 0; j < 6; ++j) {
            const int idx = tid + j * BLOCK;
            const int4 v = vg[idx];
            ushort4 s;
            s.x = (unsigned short)v.x; s.y = (unsigned short)v.y;
            s.z = (unsigned short)v.z; s.w = (unsigned short)v.w;
            ct[idx] = s;
        }
    }

    // ---- syndrome bits (2 rows/thread) ----
    int synbits = 0;
    #pragma unroll
    for (int k = 0; k < 2; ++k)
        synbits |= ((synd_b[h * HALF_M + tid + k * BLOCK] != 0.0f) ? 1 : 0) << k;

    // ---- u0 (4 packed words/thread); lvX = u0 (it=1 gather source); acc = bias ----
    int u0a, u0b, u0c, u0d;
    {
        const float4* lp = (const float4*)llr_b;
        float4 f0 = lp[2 * tid], f1 = lp[2 * tid + 1];
        u0a = (quantI(f0.x) + BIAS) | ((quantI(f0.y) + BIAS) << 16);
        u0b = (quantI(f0.z) + BIAS) | ((quantI(f0.w) + BIAS) << 16);
        u0c = (quantI(f1.x) + BIAS) | ((quantI(f1.y) + BIAS) << 16);
        u0d = (quantI(f1.z) + BIAS) | ((quantI(f1.w) + BIAS) << 16);
        ((int4*)lvX)[tid] = make_int4(u0a, u0b, u0c, u0d);
        ((int4*)acc)[tid] = make_int4((int)ACCB, (int)ACCB, (int)ACCB, (int)ACCB);
    }

    unsigned msgp[2][3];   // b_{it-1} for this thread's 2 rows, packed s8
    msgp[0][0] = msgp[0][1] = msgp[0][2] = 0u;
    msgp[1][0] = msgp[1][1] = msgp[1][2] = 0u;

    __syncthreads();

    Cols c0 = loadCols(colT, tid);
    Cols c1 = loadCols(colT, tid + BLOCK);

    int conv_it = 0;
    const int* outP = nullptr;

    // it: (CUR,NXT) alternates; l_v(8) lands in lvX. Mailbox parity P = it&1.
    ITER(1, 1, 1, lvX, lvY, 8,  false);
    ITER(2, 0, 0, lvY, lvX, 12, false);
    ITER(3, 0, 1, lvX, lvY, 14, false);
    ITER(4, 0, 0, lvY, lvX, 15, false);
    ITER(5, 0, 1, lvX, lvY, 15, true);
    ITER(6, 0, 0, lvY, lvX, 15, true);
    ITER(7, 0, 1, lvX, lvY, 15, true);
    ITER(8, 0, 0, lvY, lvX, 15, true);

    // ---- fell through: final parity of l_v(8) (in lvX), own rows only ----
    {
        const unsigned short* curS = (const unsigned short*)lvX;
        int mism = 0;
        {
            int par = 0;
            #pragma unroll
            for (int d = 0; d < RDEG; ++d) par ^= (curS[colOf(c0, d)] <= BIAS);
            mism |= par ^ (synbits & 1);
        }
        {
            int par = 0;
            #pragma unroll
            for (int d = 0; d < RDEG; ++d) par ^= (curS[colOf(c1, d)] <= BIAS);
            mism |= par ^ ((synbits >> 1) & 1);
        }
        if (__any(mism) && (tid & 63) == 0) atomicMax(&lastbad_g[b], MAXIT + 1);
        SYNCPAIR(9);
        if (lb_sh < MAXIT + 1) conv_it = MAXIT;
        outP = lvX;
    }

done_label: ;
    // ---- outputs: [e_out | num_iters | l_out | converges], float32 flat.
    // Each half writes its own 2048 words (4096 variables) of e/l.
    const int   num = conv_it ? conv_it : MAXIT;
    const float cv  = conv_it ? 1.0f : 0.0f;
    float* e_out   = out;
    float* num_out = out + (size_t)BB * NN;
    float* l_out   = num_out + BB;
    float* c_out   = l_out + (size_t)BB * NN;
    #pragma unroll
    for (int j = 0; j < 2; ++j) {
        const int w  = h * (NW / 2) + tid + j * BLOCK;   // word in [h*2048, h*2048+2048)
        const int wv = outP[w];
        const int l0 = (wv & 0xffff) - BIAS;
        const int l1 = ((wv >> 16) & 0xffff) - BIAS;
        float2 e, l;
        e.x = (l0 <= 0) ? 1.0f : 0.0f;
        e.y = (l1 <= 0) ? 1.0f : 0.0f;
        l.x = (float)clamp8(l0) * 0.0625f;
        l.y = (float)clamp8(l1) * 0.0625f;
        ((float2*)(e_out + (size_t)b * NN))[w] = e;
        ((float2*)(l_out + (size_t)b * NN))[w] = l;
    }
    if (tid == 0 && h == 0) { num_out[b] = (float)num; c_out[b] = cv; }
}

extern "C" void kernel_launch(void* const* d_in, const int* in_sizes, int n_in,
                              void* d_out, int out_size, void* d_ws, size_t ws_size,
                              hipStream_t stream) {
    (void)in_sizes; (void)n_in; (void)ws_size; (void)out_size;
    const float* synd = (const float*)d_in[0];
    const float* llr0 = (const float*)d_in[1];
    const int*   Vcol = (const int*)d_in[3];   // V_c_col
    float*       out  = (float*)d_out;
    // Zero the pairwise-sync flags + per-batch lastbad every call (graph-safe).
    hipMemsetAsync(d_ws, 0, (NFLAGS + BB) * sizeof(int), stream);
    ldpc_kernel<<<2 * BB, BLOCK, 0, stream>>>(synd, llr0, Vcol, out, (int*)d_ws);
}

// Round 12
// 100.756 us; speedup vs baseline: 8.0711x; 8.0711x over previous
//
#include <hip/hip_runtime.h>

#define BB     128
#define MM     4096
#define NN     8192
#define DEG    12
#define RDEG   11          // edges 0..10 real; edge 11 is ALWAYS the dummy (col==NN)
#define MAXIT  8
#define BLOCK  1024
#define RPT    (MM / BLOCK)
#define NW     (NN / 2)    // l_v packed: 2 vars per word, u16 halves biased +32768
#define BIAS   32768
#define BIG    (1 << 20)

__device__ __forceinline__ int quantI(float x) {   // fp2fxp -> integer units of 1/16
    float r = rintf(x * 16.0f);                    // RNE, matches jnp.round
    r = fminf(r, 127.0f);
    r = fmaxf(r, -128.0f);
    return (int)r;
}
__device__ __forceinline__ int clamp8(int t) { return max(-128, min(127, t)); }
__device__ __forceinline__ int rne4(int t) {       // RNE of t/16, t >= 0
    const int r = t >> 4, rem = t & 15;
    return r + (((rem > 8) || (rem == 8 && (r & 1))) ? 1 : 0);
}

// Columns live in LDS (u16). One row = 12 u16 = 24 B -> three ds_read_b64.
struct Cols { ushort4 a, b, c; };
__device__ __forceinline__ Cols loadCols(const unsigned short* colT, int row) {
    const ushort4* p = (const ushort4*)(colT + row * DEG);
    Cols C; C.a = p[0]; C.b = p[1]; C.c = p[2]; return C;
}
__device__ __forceinline__ int colOf(const Cols& C, int d) {
    switch (d) {
        case 0: return C.a.x; case 1: return C.a.y; case 2: return C.a.z; case 3: return C.a.w;
        case 4: return C.b.x; case 5: return C.b.y; case 6: return C.b.z; case 7: return C.b.w;
        case 8: return C.c.x; case 9: return C.c.y; default: return C.c.z;
    }
}

// One check-row. FIRSTF==1: it=1 (m=0, so a = u0[col] = message0; dummy = +inf
// excluded from mins; no parity/mism). Else: dummy joins mins as 127, parity of
// l_v(it-1) fused into the gather, msg subtracted. NEXTCODE runs at the register
// low point (aa[] collapsed into eqb) and issues the next row's gathers.
#define ROW(KK, FIRSTF, LU, CC_, NXTA, FBI, FB1, NEXTCODE) do {                \
    int sbits = 0, par = 0, min0 = BIG, min1 = BIG;                            \
    int aa[RDEG];                                                              \
    _Pragma("unroll") for (int d = 0; d < RDEG; ++d) {                         \
        const int m = FIRSTF ? 0 :                                             \
            (int)(signed char)((msgp[KK][d >> 2] >> ((d & 3) * 8)) & 0xffu);   \
        const int l = LU[d] - BIAS;                                            \
        par ^= (l <= 0);                                                       \
        const int av = clamp8(l - m);                                          \
        const int t = abs(av);                                                 \
        sbits |= (av <= 0) << d;                                               \
        min1 = min(min1, max(min0, t)); min0 = min(min0, t);                   \
        aa[d] = t; }                                                           \
    if (!FIRSTF) {                                                             \
        /* dummy edge a = fxp(inf-0) = 7.9375 -> 127: joins mins, clamps both */\
        min1 = min(min1, max(min0, 127)); min0 = min(min0, 127);               \
        mism |= par ^ ((synbits >> KK) & 1); }                                 \
    int eqb = 0;                                                               \
    _Pragma("unroll") for (int d = 0; d < RDEG; ++d)                           \
        eqb |= (aa[d] == min0) << d;                                           \
    NEXTCODE;                                                                  \
    const int qsb = ((synbits >> KK) & 1) ^ (__popc(sbits) & 1);               \
    const int m0C = FIRSTF ? min(min0, 127) : min0;  /* non-first already <=127 */ \
    const int m1C = FIRSTF ? min(min1, 127) : min1;                            \
    const int q0 = FB1 ? m0C : rne4(m0C * FBI);                                \
    const int q1 = FB1 ? m1C : rne4(m1C * FBI);                                \
    unsigned nm0 = 0u, nm1 = 0u, nm2 = 0u;                                     \
    _Pragma("unroll") for (int d = 0; d < RDEG; ++d) {                         \
        const int q = ((eqb >> d) & 1) ? q1 : q0;                              \
        const int s = ((sbits >> d) & 1) ^ qsb;                                \
        const int bv = s ? -q : q;                                             \
        if (d < 4)      nm0 |= ((unsigned)bv & 0xffu) << (d * 8);              \
        else if (d < 8) nm1 |= ((unsigned)bv & 0xffu) << ((d - 4) * 8);        \
        else            nm2 |= ((unsigned)bv & 0xffu) << ((d - 8) * 8);        \
        if (bv != 0) {                                                         \
            const int col = colOf(CC_, d);                                     \
            atomicAdd(&NXTA[col >> 1], (int)((unsigned)bv << ((col & 1) << 4))); } } \
    msgp[KK][0] = nm0; msgp[KK][1] = nm1; msgp[KK][2] = nm2;                   \
} while (0)

// One iteration. c0,c1 are PERSISTENT and already valid at entry (prefetched
// before the previous barrier) -> row-0 gathers issue immediately after the
// barrier. ROW(3)'s tail reloads c0,c1 for the NEXT iteration (colT is static,
// so reading it before the barrier is race-free).
#define ITER(IT, FIRSTF, HAVERST, CURA, NXTA, RSTA, FBI, FB1) {                \
    const unsigned short* curS = (const unsigned short*)(CURA);                \
    int mism = 0; (void)mism;                                                  \
    int luA[RDEG], luB[RDEG];                                                  \
    _Pragma("unroll") for (int d = 0; d < RDEG; ++d)                           \
        luA[d] = (int)curS[colOf(c0, d)];                                      \
    if (HAVERST) ((int4*)(RSTA))[tid] = make_int4(u0a, u0b, u0c, u0d);         \
    Cols c2, c3;                                                               \
    ROW(0, FIRSTF, luA, c0, NXTA, FBI, FB1, {                                  \
        _Pragma("unroll") for (int d = 0; d < RDEG; ++d)                       \
            luB[d] = (int)curS[colOf(c1, d)];                                  \
        c2 = loadCols(colT, tid + 2 * BLOCK); });                              \
    ROW(1, FIRSTF, luB, c1, NXTA, FBI, FB1, {                                  \
        _Pragma("unroll") for (int d = 0; d < RDEG; ++d)                       \
            luA[d] = (int)curS[colOf(c2, d)];                                  \
        c3 = loadCols(colT, tid + 3 * BLOCK); });                              \
    ROW(2, FIRSTF, luA, c2, NXTA, FBI, FB1, {                                  \
        _Pragma("unroll") for (int d = 0; d < RDEG; ++d)                       \
            luB[d] = (int)curS[colOf(c3, d)]; });                              \
    ROW(3, FIRSTF, luB, c3, NXTA, FBI, FB1, {                                  \
        c0 = loadCols(colT, tid);                                              \
        c1 = loadCols(colT, tid + BLOCK); });                                  \
    if (!FIRSTF) {                                                             \
        if (__any(mism) && (tid & 63) == 0) atomicMax(&lastbad, IT);           \
    }                                                                          \
    __syncthreads();                                                           \
    if (!FIRSTF && lastbad < IT) { conv_it = IT - 1; outP = CURA; goto done_label; } \
}

__global__ __launch_bounds__(BLOCK, 4)
__attribute__((amdgpu_waves_per_eu(4, 4)))
void ldpc_kernel(const float* __restrict__ synd,
                 const float* __restrict__ llr0,
                 const int*  __restrict__ Vcol,
                 float* __restrict__ out)
{
    __shared__ __align__(16) int lvA[NW];                    // 16 KB each
    __shared__ __align__(16) int lvB[NW];
    __shared__ __align__(16) int lvC[NW];
    __shared__ __align__(16) unsigned short colT[MM * DEG];  // 96 KB column table
    __shared__ int lastbad;                                  // total ~148 KB LDS

    const int b   = blockIdx.x;
    const int tid = threadIdx.x;
    const float* llr_b  = llr0 + (size_t)b * NN;
    const float* synd_b = synd + (size_t)b * MM;

    // ---- fill colT from global (coalesced int4 reads, ushort4 LDS writes) ----
    {
        const int4* vg = (const int4*)Vcol;      // 12288 int4s
        ushort4*    ct = (ushort4*)colT;
        #pragma unroll
        for (int j = 0; j < 12; ++j) {
            const int idx = tid + j * BLOCK;
            const int4 v = vg[idx];
            ushort4 s;
            s.x = (unsigned short)v.x; s.y = (unsigned short)v.y;
            s.z = (unsigned short)v.z; s.w = (unsigned short)v.w;
            ct[idx] = s;
        }
    }

    // ---- syndrome bits ----
    int synbits = 0;
    #pragma unroll
    for (int k = 0; k < RPT; ++k)
        synbits |= ((synd_b[tid + k * BLOCK] != 0.0f) ? 1 : 0) << k;

    // ---- u0 in 4 named scalars; thread owns words 4t..4t+3; lvA = lvB = u0 ----
    int u0a, u0b, u0c, u0d;
    {
        const float4* lp = (const float4*)llr_b;
        float4 f0 = lp[2 * tid], f1 = lp[2 * tid + 1];
        u0a = (quantI(f0.x) + BIAS) | ((quantI(f0.y) + BIAS) << 16);
        u0b = (quantI(f0.z) + BIAS) | ((quantI(f0.w) + BIAS) << 16);
        u0c = (quantI(f1.x) + BIAS) | ((quantI(f1.y) + BIAS) << 16);
        u0d = (quantI(f1.z) + BIAS) | ((quantI(f1.w) + BIAS) << 16);
        ((int4*)lvA)[tid] = make_int4(u0a, u0b, u0c, u0d);   // it=1 scatter target
        ((int4*)lvB)[tid] = make_int4(u0a, u0b, u0c, u0d);   // it=1 gather source
    }
    if (tid == 0) lastbad = 1;

    // msg history starts at 0: it=1's gather of u0 then IS message0.
    unsigned msgp[RPT][3];
    #pragma unroll
    for (int k = 0; k < RPT; ++k) { msgp[k][0] = 0u; msgp[k][1] = 0u; msgp[k][2] = 0u; }

    __syncthreads();   // colT + lvA/lvB visible

    Cols c0 = loadCols(colT, tid);
    Cols c1 = loadCols(colT, tid + BLOCK);

    int conv_it = 0;
    const int* outP = nullptr;

    // ---- it = 1..8; rotation: NXT is always u0 at entry, RST preps it+1 ----
    ITER(1, 1, 0, lvB, lvA, lvC, 8,  false);   // lvA = l_v(1); lvB stays u0
    ITER(2, 0, 1, lvA, lvB, lvC, 12, false);   // lvB = l_v(2); lvC -> u0
    ITER(3, 0, 1, lvB, lvC, lvA, 14, false);
    ITER(4, 0, 1, lvC, lvA, lvB, 15, false);
    ITER(5, 0, 1, lvA, lvB, lvC, 15, true);
    ITER(6, 0, 1, lvB, lvC, lvA, 15, true);
    ITER(7, 0, 1, lvC, lvA, lvB, 15, true);
    ITER(8, 0, 0, lvA, lvB, lvC, 15, true);    // l_v(8) -> lvB; no reset needed

    // ---- fell through: final parity check on l_v(8) (in lvB) ----
    {
        const unsigned short* curS = (const unsigned short*)lvB;
        const Cols d2 = loadCols(colT, tid + 2 * BLOCK);
        const Cols d3 = loadCols(colT, tid + 3 * BLOCK);
        int mism = 0;
        {
            int par = 0;
            #pragma unroll
            for (int d = 0; d < RDEG; ++d) par ^= (curS[colOf(c0, d)] <= BIAS);
            mism |= par ^ (synbits & 1);
        }
        {
            int par = 0;
            #pragma unroll
            for (int d = 0; d < RDEG; ++d) par ^= (curS[colOf(c1, d)] <= BIAS);
            mism |= par ^ ((synbits >> 1) & 1);
        }
        {
            int par = 0;
            #pragma unroll
            for (int d = 0; d < RDEG; ++d) par ^= (curS[colOf(d2, d)] <= BIAS);
            mism |= par ^ ((synbits >> 2) & 1);
        }
        {
            int par = 0;
            #pragma unroll
            for (int d = 0; d < RDEG; ++d) par ^= (curS[colOf(d3, d)] <= BIAS);
            mism |= par ^ ((synbits >> 3) & 1);
        }
        if (__any(mism) && (tid & 63) == 0) atomicMax(&lastbad, MAXIT + 1);
        __syncthreads();
        if (lastbad < MAXIT + 1) conv_it = MAXIT;
        outP = lvB;
    }

done_label: ;
    // ---- outputs: [e_out | num_iters | l_out | converges], float32 flat ----
    const int   num = conv_it ? conv_it : MAXIT;
    const float cv  = conv_it ? 1.0f : 0.0f;
    float* e_out   = out;
    float* num_out = out + (size_t)BB * NN;
    float* l_out   = num_out + BB;
    float* c_out   = l_out + (size_t)BB * NN;
    #pragma unroll
    for (int j = 0; j < 4; ++j) {
        const int w  = tid + j * BLOCK;
        const int wv = outP[w];
        const int l0 = (wv & 0xffff) - BIAS;
        const int l1 = ((wv >> 16) & 0xffff) - BIAS;
        float2 e, l;
        e.x = (l0 <= 0) ? 1.0f : 0.0f;
        e.y = (l1 <= 0) ? 1.0f : 0.0f;
        l.x = (float)clamp8(l0) * 0.0625f;
        l.y = (float)clamp8(l1) * 0.0625f;
        ((float2*)(e_out + (size_t)b * NN))[w] = e;
        ((float2*)(l_out + (size_t)b * NN))[w] = l;
    }
    if (tid == 0) { num_out[b] = (float)num; c_out[b] = cv; }
}

extern "C" void kernel_launch(void* const* d_in, const int* in_sizes, int n_in,
                              void* d_out, int out_size, void* d_ws, size_t ws_size,
                              hipStream_t stream) {
    (void)in_sizes; (void)n_in; (void)d_ws; (void)ws_size; (void)out_size;
    const float* synd = (const float*)d_in[0];
    const float* llr0 = (const float*)d_in[1];
    const int*   Vcol = (const int*)d_in[3];   // V_c_col
    float*       out  = (float*)d_out;
    ldpc_kernel<<<BB, BLOCK, 0, stream>>>(synd, llr0, Vcol, out);
}